// Round 9
// baseline (258.386 us; speedup 1.0000x reference)
//
#include <hip/hip_runtime.h>

#define BN_EPS 1e-5f
#define CCH 2048   // edges per partition block (391 blocks -> better CU coverage)
#define NSLICE 32  // stats partial slices (contention limiter)

// ---------------- bf16 helpers ----------------

__device__ inline unsigned pack_bf16x2(float x, float y) {
    unsigned ux = __float_as_uint(x);
    ux = (ux + 0x7FFFu + ((ux >> 16) & 1u)) >> 16;
    unsigned uy = __float_as_uint(y);
    uy = (uy + 0x7FFFu + ((uy >> 16) & 1u)) >> 16;
    return ux | (uy << 16);
}

__device__ inline void bf16x2_add(unsigned u, float& a, float& b) {
    a += __uint_as_float((u & 0xFFFFu) << 16);
    b += __uint_as_float(u & 0xFFFF0000u);
}

__device__ inline float bf16_lo(unsigned u) { return __uint_as_float((u & 0xFFFFu) << 16); }
__device__ inline float bf16_hi(unsigned u) { return __uint_as_float(u & 0xFFFF0000u); }

// ================= Phase A: coarse-bucket counting (buckets of 256 dst) =================

__global__ __launch_bounds__(256) void coarse_count(const int* __restrict__ dst,
                                                    int* __restrict__ ccnt, int E) {
    __shared__ int h[256];
    int t = threadIdx.x;
    h[t] = 0;
    __syncthreads();
    int e0 = blockIdx.x * CCH;
#pragma unroll
    for (int k = 0; k < CCH / 256; ++k) {
        int e = e0 + k * 256 + t;
        if (e < E) atomicAdd(&h[dst[e] >> 8], 1);
    }
    __syncthreads();
    if (h[t]) atomicAdd(&ccnt[t], h[t]);
}

// exclusive scan of ccnt -> cboff/gcur; rp[n]=E; zero cnt_g and out.
__global__ __launch_bounds__(256) void cscan(const int* __restrict__ ccnt,
                                             int* __restrict__ cboff,
                                             int* __restrict__ gcur,
                                             int* __restrict__ rp,
                                             float* __restrict__ cnt_g,
                                             float* __restrict__ out,
                                             int NBC, int n, int E, int G) {
    __shared__ int s[256];
    int t = threadIdx.x;
    int v = (t < NBC) ? ccnt[t] : 0;
    s[t] = v;
    __syncthreads();
    for (int off = 1; off < 256; off <<= 1) {
        int u = (t >= off) ? s[t - off] : 0;
        __syncthreads();
        s[t] += u;
        __syncthreads();
    }
    int ex = s[t] - v;
    if (t < NBC) { cboff[t] = ex; gcur[t] = ex; }
    if (t == 0) { cboff[NBC] = E; rp[n] = E; }
    for (int i = t; i < G; i += 256) cnt_g[i] = 0.f;
    int tot = G * 64;
    for (int i = t; i < tot; i += 256) out[i] = 0.f;
}

// Phase A scatter: per-block run reservation -> line-granular writes of packed (src<<8|dstLow8)
__global__ __launch_bounds__(256) void cscatter(const int* __restrict__ src,
                                                const int* __restrict__ dst,
                                                int* __restrict__ gcur,
                                                unsigned* __restrict__ tmp, int E) {
    __shared__ int lcnt[256];
    int t = threadIdx.x;
    int e0 = blockIdx.x * CCH;
    lcnt[t] = 0;
    __syncthreads();
#pragma unroll
    for (int k = 0; k < CCH / 256; ++k) {
        int e = e0 + k * 256 + t;
        if (e < E) atomicAdd(&lcnt[dst[e] >> 8], 1);
    }
    __syncthreads();
    int c = lcnt[t];
    __syncthreads();
    if (c > 0) lcnt[t] = atomicAdd(&gcur[t], c);
    __syncthreads();
#pragma unroll
    for (int k = 0; k < CCH / 256; ++k) {
        int e = e0 + k * 256 + t;
        if (e < E) {
            int d = dst[e];
            int pos = atomicAdd(&lcnt[d >> 8], 1);
            tmp[pos] = ((unsigned)src[e] << 8) | (unsigned)(d & 255);
        }
    }
}

// ================= Phase B: per-bucket counting sort -> CSR (rp, u16 col) + dinv
//                   + fused graph-size histogram (tail) =================

#define OUT_CAP 8192

__global__ __launch_bounds__(256) void build_csr(const unsigned* __restrict__ tmp,
                                                 const int* __restrict__ cboff,
                                                 int* __restrict__ rp,
                                                 unsigned short* __restrict__ col,
                                                 float* __restrict__ dinv,
                                                 const int* __restrict__ batch,
                                                 float* __restrict__ cnt_g,
                                                 int n, int G) {
    __shared__ int hist[256];
    __shared__ int sc[256];
    __shared__ unsigned short outw[OUT_CAP];
    __shared__ int h[512];
    int b = blockIdx.x;
    int t = threadIdx.x;
    int beg = cboff[b], end = cboff[b + 1];
    int m = end - beg;
    hist[t] = 0;
    __syncthreads();
    for (int e = beg + t; e < end; e += 256) atomicAdd(&hist[tmp[e] & 255u], 1);
    __syncthreads();
    int v = hist[t];
    sc[t] = v;
    __syncthreads();
    for (int off = 1; off < 256; off <<= 1) {
        int u = (t >= off) ? sc[t - off] : 0;
        __syncthreads();
        sc[t] += u;
        __syncthreads();
    }
    int excl = sc[t] - v;
    int node = b * 256 + t;
    if (node < n) {
        dinv[node] = rsqrtf(1.0f + (float)v);
        rp[node] = beg + excl;
    }
    hist[t] = excl;  // becomes cursor
    __syncthreads();
    if (m <= OUT_CAP) {
        for (int e = beg + t; e < end; e += 256) {
            unsigned p = tmp[e];
            int pos = atomicAdd(&hist[p & 255u], 1);
            outw[pos] = (unsigned short)(p >> 8);
        }
        __syncthreads();
        for (int i = t; i < m; i += 256) col[beg + i] = outw[i];
    } else {  // overflow fallback
        for (int e = beg + t; e < end; e += 256) {
            unsigned p = tmp[e];
            int pos = atomicAdd(&hist[p & 255u], 1);
            col[beg + pos] = (unsigned short)(p >> 8);
        }
    }
    // ---- fused graph-size histogram ----
    if (G <= 512) {
        __syncthreads();
        for (int i = t; i < 512; i += 256) h[i] = 0;
        __syncthreads();
        for (int i = b * 256 + t; i < n; i += gridDim.x * 256)
            atomicAdd(&h[batch[i]], 1);
        __syncthreads();
        for (int i = t; i < G; i += 256)
            if (h[i]) atomicAdd(&cnt_g[i], (float)h[i]);
    } else {
        for (int i = b * 256 + t; i < n; i += gridDim.x * 256)
            atomicAdd(&cnt_g[batch[i]], 1.0f);
    }
}

// ================= GEMM: Hs(bf16) = BNReLU(X) @ W * dinv[row] =================
// x_bf16=0: X is fp32 (layer 1, no BN). x_bf16=1: X is bf16 Ybuf, BN+ReLU
// applied during unpack; BN coefficients computed in-block from prev layer's
// stat partials (16 KB L2-broadcast read per block).

#define SXS 68

__global__ __launch_bounds__(256) void gemm64_v2(const void* __restrict__ Xv,
                                                 const float* __restrict__ W,
                                                 const float* __restrict__ dinv,
                                                 const float* __restrict__ part,
                                                 const float* __restrict__ gamma,
                                                 const float* __restrict__ beta,
                                                 int x_bf16, float inv_n,
                                                 unsigned* __restrict__ Hs, int n) {
    __shared__ float sX[64 * SXS];
    __shared__ float sW[64 * SXS];
    __shared__ float s_scsh[128];
    int t = threadIdx.x;
    int c4 = t & 15;
    int base = blockIdx.x * 64;

    if (x_bf16) {
        if (t < 128) {
            float s = 0.f;
#pragma unroll
            for (int k = 0; k < NSLICE; ++k) s += part[k * 128 + t];
            s_scsh[t] = s;
        }
        __syncthreads();
        if (t < 64) {
            float mean = s_scsh[t] * inv_n;
            float var = s_scsh[64 + t] * inv_n - mean * mean;
            float sc = gamma[t] * rsqrtf(var + BN_EPS);
            s_scsh[t] = sc;
            s_scsh[64 + t] = beta[t] - mean * sc;
        }
        __syncthreads();
    }

    {
        const float4* W4 = (const float4*)W;
#pragma unroll
        for (int it = 0; it < 4; ++it) {
            int idx = it * 256 + t;
            int r = idx >> 4;
            float4 v = W4[r * 16 + c4];
            *(float4*)&sW[r * SXS + c4 * 4] = v;
        }
    }
    if (x_bf16) {
        const uint2* X2 = (const uint2*)Xv;
        float4 sc4 = *(const float4*)&s_scsh[c4 * 4];
        float4 sh4 = *(const float4*)&s_scsh[64 + c4 * 4];
#pragma unroll
        for (int it = 0; it < 4; ++it) {
            int idx = it * 256 + t;
            int r = idx >> 4;
            int grow = base + r;
            float4 v = make_float4(0.f, 0.f, 0.f, 0.f);
            if (grow < n) {
                uint2 u = X2[(size_t)grow * 16 + c4];
                v.x = bf16_lo(u.x); v.y = bf16_hi(u.x);
                v.z = bf16_lo(u.y); v.w = bf16_hi(u.y);
            }
            v.x = fmaxf(fmaf(v.x, sc4.x, sh4.x), 0.f);
            v.y = fmaxf(fmaf(v.y, sc4.y, sh4.y), 0.f);
            v.z = fmaxf(fmaf(v.z, sc4.z, sh4.z), 0.f);
            v.w = fmaxf(fmaf(v.w, sc4.w, sh4.w), 0.f);
            *(float4*)&sX[r * SXS + c4 * 4] = v;
        }
    } else {
        const float4* X4 = (const float4*)Xv;
#pragma unroll
        for (int it = 0; it < 4; ++it) {
            int idx = it * 256 + t;
            int r = idx >> 4;
            int grow = base + r;
            float4 v = make_float4(0.f, 0.f, 0.f, 0.f);
            if (grow < n) v = X4[(size_t)grow * 16 + c4];
            *(float4*)&sX[r * SXS + c4 * 4] = v;
        }
    }
    __syncthreads();

    int rgrp = t >> 4;
    float4 acc[4];
#pragma unroll
    for (int ri = 0; ri < 4; ++ri) acc[ri] = make_float4(0.f, 0.f, 0.f, 0.f);

#pragma unroll 4
    for (int k4 = 0; k4 < 16; ++k4) {
        float4 xv[4], wv[4];
#pragma unroll
        for (int ri = 0; ri < 4; ++ri)
            xv[ri] = *(const float4*)&sX[(rgrp + 16 * ri) * SXS + k4 * 4];
#pragma unroll
        for (int kk = 0; kk < 4; ++kk)
            wv[kk] = *(const float4*)&sW[(k4 * 4 + kk) * SXS + c4 * 4];
#pragma unroll
        for (int ri = 0; ri < 4; ++ri) {
            acc[ri].x = fmaf(xv[ri].x, wv[0].x, acc[ri].x);
            acc[ri].y = fmaf(xv[ri].x, wv[0].y, acc[ri].y);
            acc[ri].z = fmaf(xv[ri].x, wv[0].z, acc[ri].z);
            acc[ri].w = fmaf(xv[ri].x, wv[0].w, acc[ri].w);
            acc[ri].x = fmaf(xv[ri].y, wv[1].x, acc[ri].x);
            acc[ri].y = fmaf(xv[ri].y, wv[1].y, acc[ri].y);
            acc[ri].z = fmaf(xv[ri].y, wv[1].z, acc[ri].z);
            acc[ri].w = fmaf(xv[ri].y, wv[1].w, acc[ri].w);
            acc[ri].x = fmaf(xv[ri].z, wv[2].x, acc[ri].x);
            acc[ri].y = fmaf(xv[ri].z, wv[2].y, acc[ri].y);
            acc[ri].z = fmaf(xv[ri].z, wv[2].z, acc[ri].z);
            acc[ri].w = fmaf(xv[ri].z, wv[2].w, acc[ri].w);
            acc[ri].x = fmaf(xv[ri].w, wv[3].x, acc[ri].x);
            acc[ri].y = fmaf(xv[ri].w, wv[3].y, acc[ri].y);
            acc[ri].z = fmaf(xv[ri].w, wv[3].z, acc[ri].z);
            acc[ri].w = fmaf(xv[ri].w, wv[3].w, acc[ri].w);
        }
    }

#pragma unroll
    for (int ri = 0; ri < 4; ++ri) {
        int row = base + rgrp + 16 * ri;
        if (row < n) {
            float dv = dinv[row];
            uint2 o2;
            o2.x = pack_bf16x2(acc[ri].x * dv, acc[ri].y * dv);
            o2.y = pack_bf16x2(acc[ri].z * dv, acc[ri].w * dv);
            ((uint2*)Hs)[(size_t)row * 16 + c4] = o2;
        }
    }
}

// ================= CSR gather-aggregate (bf16 Hs) + fused BN-stat partials =================
// Y written as bf16 (uint2); stats accumulated on fp32 pre-rounding values.

__global__ __launch_bounds__(256) void agg(const uint2* __restrict__ Hs2,
                                           const int* __restrict__ rp,
                                           const unsigned short* __restrict__ col,
                                           const float* __restrict__ dinv,
                                           unsigned* __restrict__ Yb,
                                           float* __restrict__ part, int n) {
    __shared__ float sS[4][64];
    __shared__ float sQ[4][64];
    int t = threadIdx.x;
    int w = t >> 6;
    int lane = t & 63;
    int q = lane >> 4;
    int c = lane & 15;
    int d = blockIdx.x * 4 + w;
    bool valid = d < n;
    int dc = valid ? d : 0;
    float ax = 0.f, ay = 0.f, az = 0.f, aw = 0.f;
    int beg = valid ? rp[dc] : 0;
    int end = valid ? rp[dc + 1] : 0;
    for (int b = beg; b < end; b += 64) {
        int m = min(64, end - b);
        int myidx = (lane < m) ? (int)col[b + lane] : 0;
        int jj = 0;
        for (; jj + 7 < m; jj += 8) {
            int s0 = __shfl(myidx, jj + q, 64);
            int s1 = __shfl(myidx, jj + 4 + q, 64);
            uint2 v0 = Hs2[(size_t)s0 * 16 + c];
            uint2 v1 = Hs2[(size_t)s1 * 16 + c];
            bf16x2_add(v0.x, ax, ay); bf16x2_add(v0.y, az, aw);
            bf16x2_add(v1.x, ax, ay); bf16x2_add(v1.y, az, aw);
        }
        for (; jj < m; jj += 4) {
            int e = jj + q;
            int s0 = __shfl(myidx, min(e, m - 1), 64);
            if (e < m) {
                uint2 v = Hs2[(size_t)s0 * 16 + c];
                bf16x2_add(v.x, ax, ay); bf16x2_add(v.y, az, aw);
            }
        }
    }
    ax += __shfl_xor(ax, 16, 64); ay += __shfl_xor(ay, 16, 64);
    az += __shfl_xor(az, 16, 64); aw += __shfl_xor(aw, 16, 64);
    ax += __shfl_xor(ax, 32, 64); ay += __shfl_xor(ay, 32, 64);
    az += __shfl_xor(az, 32, 64); aw += __shfl_xor(aw, 32, 64);
    if (q == 0) {
        float4 y = make_float4(0.f, 0.f, 0.f, 0.f);
        if (valid) {
            float hx = 0.f, hy = 0.f, hz = 0.f, hw = 0.f;
            uint2 hv = Hs2[(size_t)dc * 16 + c];
            bf16x2_add(hv.x, hx, hy); bf16x2_add(hv.y, hz, hw);
            float dv = dinv[dc];
            y.x = (ax + hx) * dv; y.y = (ay + hy) * dv;
            y.z = (az + hz) * dv; y.w = (aw + hw) * dv;
            uint2 o2;
            o2.x = pack_bf16x2(y.x, y.y);
            o2.y = pack_bf16x2(y.z, y.w);
            ((uint2*)Yb)[(size_t)dc * 16 + c] = o2;
        }
        *(float4*)&sS[w][c * 4] = y;
        float4 yq = make_float4(y.x * y.x, y.y * y.y, y.z * y.z, y.w * y.w);
        *(float4*)&sQ[w][c * 4] = yq;
    }
    __syncthreads();
    if (t < 64) {
        float s = sS[0][t] + sS[1][t] + sS[2][t] + sS[3][t];
        float qq = sQ[0][t] + sQ[1][t] + sQ[2][t] + sQ[3][t];
        float* dst = part + (size_t)(blockIdx.x & (NSLICE - 1)) * 128;
        atomicAdd(&dst[t], s);
        atomicAdd(&dst[64 + t], qq);
    }
}

// layer-3 variant: no Y materialization; per-graph raw-y sums via atomics.
__global__ __launch_bounds__(256) void agg_pool(const uint2* __restrict__ Hs2,
                                                const int* __restrict__ rp,
                                                const unsigned short* __restrict__ col,
                                                const float* __restrict__ dinv,
                                                const int* __restrict__ batch,
                                                float* __restrict__ out,
                                                float* __restrict__ part, int n) {
    __shared__ float sS[4][64];
    __shared__ float sQ[4][64];
    __shared__ int sG[4];
    int t = threadIdx.x;
    int w = t >> 6;
    int lane = t & 63;
    int q = lane >> 4;
    int c = lane & 15;
    int d = blockIdx.x * 4 + w;
    bool valid = d < n;
    int dc = valid ? d : 0;
    float ax = 0.f, ay = 0.f, az = 0.f, aw = 0.f;
    int beg = valid ? rp[dc] : 0;
    int end = valid ? rp[dc + 1] : 0;
    for (int b = beg; b < end; b += 64) {
        int m = min(64, end - b);
        int myidx = (lane < m) ? (int)col[b + lane] : 0;
        int jj = 0;
        for (; jj + 7 < m; jj += 8) {
            int s0 = __shfl(myidx, jj + q, 64);
            int s1 = __shfl(myidx, jj + 4 + q, 64);
            uint2 v0 = Hs2[(size_t)s0 * 16 + c];
            uint2 v1 = Hs2[(size_t)s1 * 16 + c];
            bf16x2_add(v0.x, ax, ay); bf16x2_add(v0.y, az, aw);
            bf16x2_add(v1.x, ax, ay); bf16x2_add(v1.y, az, aw);
        }
        for (; jj < m; jj += 4) {
            int e = jj + q;
            int s0 = __shfl(myidx, min(e, m - 1), 64);
            if (e < m) {
                uint2 v = Hs2[(size_t)s0 * 16 + c];
                bf16x2_add(v.x, ax, ay); bf16x2_add(v.y, az, aw);
            }
        }
    }
    ax += __shfl_xor(ax, 16, 64); ay += __shfl_xor(ay, 16, 64);
    az += __shfl_xor(az, 16, 64); aw += __shfl_xor(aw, 16, 64);
    ax += __shfl_xor(ax, 32, 64); ay += __shfl_xor(ay, 32, 64);
    az += __shfl_xor(az, 32, 64); aw += __shfl_xor(aw, 32, 64);
    if (q == 0) {
        float4 y = make_float4(0.f, 0.f, 0.f, 0.f);
        if (valid) {
            float hx = 0.f, hy = 0.f, hz = 0.f, hw = 0.f;
            uint2 hv = Hs2[(size_t)dc * 16 + c];
            bf16x2_add(hv.x, hx, hy); bf16x2_add(hv.y, hz, hw);
            float dv = dinv[dc];
            y.x = (ax + hx) * dv; y.y = (ay + hy) * dv;
            y.z = (az + hz) * dv; y.w = (aw + hw) * dv;
        }
        *(float4*)&sS[w][c * 4] = y;
        float4 yq = make_float4(y.x * y.x, y.y * y.y, y.z * y.z, y.w * y.w);
        *(float4*)&sQ[w][c * 4] = yq;
        if (lane == 0) sG[w] = valid ? batch[dc] : -1;
    }
    __syncthreads();
    if (t < 64) {
        float s = sS[0][t] + sS[1][t] + sS[2][t] + sS[3][t];
        float qq = sQ[0][t] + sQ[1][t] + sQ[2][t] + sQ[3][t];
        float* dst = part + (size_t)(blockIdx.x & (NSLICE - 1)) * 128;
        atomicAdd(&dst[t], s);
        atomicAdd(&dst[64 + t], qq);
        int g0 = sG[0], g1 = sG[1], g2 = sG[2], g3 = sG[3];
        if (g0 >= 0 && g0 == g1 && g0 == g2 && g0 == g3) {
            atomicAdd(&out[(size_t)g0 * 64 + t], s);
        } else {
            if (g0 >= 0) atomicAdd(&out[(size_t)g0 * 64 + t], sS[0][t]);
            if (g1 >= 0) atomicAdd(&out[(size_t)g1 * 64 + t], sS[1][t]);
            if (g2 >= 0) atomicAdd(&out[(size_t)g2 * 64 + t], sS[2][t]);
            if (g3 >= 0) atomicAdd(&out[(size_t)g3 * 64 + t], sS[3][t]);
        }
    }
}

// ================= final: out = BN3-affine(graph mean), BN3 coeffs in-block =================

__global__ __launch_bounds__(256) void pool_div(float* __restrict__ out,
                                                const float* __restrict__ cnt,
                                                const float* __restrict__ part,
                                                const float* __restrict__ gamma,
                                                const float* __restrict__ beta,
                                                int G, float inv_n) {
    __shared__ float s_scsh[128];
    int t = threadIdx.x;
    if (t < 128) {
        float s = 0.f;
#pragma unroll
        for (int k = 0; k < NSLICE; ++k) s += part[k * 128 + t];
        s_scsh[t] = s;
    }
    __syncthreads();
    if (t < 64) {
        float mean = s_scsh[t] * inv_n;
        float var = s_scsh[64 + t] * inv_n - mean * mean;
        float sc = gamma[t] * rsqrtf(var + BN_EPS);
        s_scsh[t] = sc;
        s_scsh[64 + t] = beta[t] - mean * sc;
    }
    __syncthreads();
    int idx = blockIdx.x * 256 + t;
    if (idx >= G * 64) return;
    int j = idx & 63, g = idx >> 6;
    float c = cnt[g];
    out[idx] = (c > 0.5f) ? fmaf(s_scsh[j], out[idx] / c, s_scsh[64 + j]) : 0.f;
}

// ================= launch =================

extern "C" void kernel_launch(void* const* d_in, const int* in_sizes, int n_in,
                              void* d_out, int out_size, void* d_ws, size_t ws_size,
                              hipStream_t stream) {
    const float* x     = (const float*)d_in[0];
    const int*   ei    = (const int*)d_in[1];
    const int*   batch = (const int*)d_in[2];
    const float* Wl[3] = {(const float*)d_in[3], (const float*)d_in[7], (const float*)d_in[11]};
    const float* gl[3] = {(const float*)d_in[5], (const float*)d_in[9], (const float*)d_in[13]};
    const float* bl[3] = {(const float*)d_in[6], (const float*)d_in[10], (const float*)d_in[14]};
    float* out = (float*)d_out;

    int E = in_sizes[1] / 2;
    int n = in_sizes[0] / 64;
    int G = out_size / 64;
    const int* src = ei;
    const int* dst = ei + E;
    int NBC = (n + 255) / 256;  // coarse buckets (<=256 for n<=65536)
    float inv_n = 1.0f / (float)n;

    char* ws = (char*)d_ws;
    size_t off = 0;
    auto carve = [&](size_t bytes) {
        void* p = ws + off;
        off += (bytes + 255) & ~(size_t)255;
        return p;
    };
    // part + ccnt carved adjacently -> single memset covers both
    float*          part  = (float*)carve(3 * NSLICE * 128 * 4);  // 49152 B
    int*            ccnt  = (int*)carve(256 * 4);                  // 1024 B
    float*          dinv  = (float*)carve((size_t)n * 4);
    float*          cnt_g = (float*)carve((size_t)G * 4);
    unsigned*       Hs    = (unsigned*)carve((size_t)n * 32 * 4);  // n*64 bf16
    unsigned*       Ybuf  = (unsigned*)carve((size_t)n * 32 * 4);  // n*64 bf16
    int*            cboff = (int*)carve(257 * 4);
    int*            gcur  = (int*)carve(256 * 4);
    int*            rp    = (int*)carve(((size_t)n + 1) * 4);
    unsigned*       tmp   = (unsigned*)carve((size_t)E * 4);
    unsigned short* col   = (unsigned short*)carve((size_t)E * 2);

    int pgrid = (E + CCH - 1) / CCH;

    // ---- setup: one memset (part+ccnt), CSR build + dinv + counts + zeroing ----
    hipMemsetAsync(part, 0, 3 * NSLICE * 128 * 4 + 256 * 4, stream);
    coarse_count<<<pgrid, 256, 0, stream>>>(dst, ccnt, E);
    cscan<<<1, 256, 0, stream>>>(ccnt, cboff, gcur, rp, cnt_g, out, NBC, n, E, G);
    cscatter<<<pgrid, 256, 0, stream>>>(src, dst, gcur, tmp, E);
    build_csr<<<NBC, 256, 0, stream>>>(tmp, cboff, rp, col, dinv, batch, cnt_g, n, G);

    int gemm_grid = (n + 63) / 64;
    int agg_grid = (n + 3) / 4;

    // ---- 3 GCN layers ----
    const void* cur = x;
    for (int l = 0; l < 3; ++l) {
        float* part_l = part + (size_t)l * NSLICE * 128;
        const float* part_prev = (l > 0) ? part + (size_t)(l - 1) * NSLICE * 128 : part;
        gemm64_v2<<<gemm_grid, 256, 0, stream>>>(cur, Wl[l], dinv, part_prev,
                                                 l > 0 ? gl[l - 1] : gl[0],
                                                 l > 0 ? bl[l - 1] : bl[0],
                                                 l > 0 ? 1 : 0, inv_n, Hs, n);
        if (l < 2) {
            agg<<<agg_grid, 256, 0, stream>>>((const uint2*)Hs, rp, col, dinv,
                                              Ybuf, part_l, n);
        } else {
            agg_pool<<<agg_grid, 256, 0, stream>>>((const uint2*)Hs, rp, col, dinv,
                                                   batch, out, part_l, n);
        }
        cur = Ybuf;
    }

    // ---- final BN3-affine on graph means (BN3 coeffs computed in-block) ----
    pool_div<<<(G * 64 + 255) / 256, 256, 0, stream>>>(out, cnt_g,
                                                       part + 2 * NSLICE * 128,
                                                       gl[2], bl[2], G, inv_n);
}